// Round 1
// baseline (186.093 us; speedup 1.0000x reference)
//
#include <hip/hip_runtime.h>
#include <hip/hip_bf16.h>

// Problem constants
#define BB 8
#define SS 2048
#define DD 1024
#define OO 1024
#define MM (BB * SS)   // 16384
#define KK DD          // 1024
#define NN OO          // 1024
#define CC 32          // chunks
#define LL 64          // chunk length (CC*LL == SS)

typedef __bf16 bf16x8 __attribute__((ext_vector_type(8)));
typedef float floatx4 __attribute__((ext_vector_type(4)));

// ---------------- Pass A: per-chunk carries ----------------
// grid (DD/256, CC, BB), block 256. carry[(b*CC+c)*DD+d] = local scan final.
__global__ void scan_carry(const float* __restrict__ x, const float* __restrict__ A,
                           float* __restrict__ carry) {
    const int d = blockIdx.x * 256 + threadIdx.x;
    const int c = blockIdx.y;
    const int b = blockIdx.z;
    const float a = A[d];
    const float* xp = x + ((size_t)b * SS + (size_t)c * LL) * DD + d;
    float h = 0.f;
#pragma unroll 16
    for (int t = 0; t < LL; ++t) {
        h = fmaf(h, a, xp[(size_t)t * DD]);
    }
    carry[((size_t)b * CC + c) * DD + d] = h;
}

// ---------------- Pass B: chunk-level scan ----------------
// grid (BB*DD/256), block 256. Hprev[(b*CC+c)*DD+d] = true state entering chunk c.
__global__ void chunk_scan(const float* __restrict__ carry, const float* __restrict__ A,
                           float* __restrict__ Hprev) {
    const int idx = blockIdx.x * 256 + threadIdx.x;   // b*DD + d
    const int d = idx & (DD - 1);
    const int b = idx >> 10;
    const float a = A[d];
    float aL = a;
#pragma unroll
    for (int i = 0; i < 6; ++i) aL *= aL;             // a^64
    float h = 0.f;
#pragma unroll
    for (int c = 0; c < CC; ++c) {
        const size_t o = ((size_t)b * CC + c) * DD + d;
        Hprev[o] = h;
        h = fmaf(aL, h, carry[o]);
    }
}

// ---------------- Pass C: emit hs (bf16) ----------------
// grid (DD/256, CC, BB), block 256.
__global__ void scan_emit(const float* __restrict__ x, const float* __restrict__ A,
                          const float* __restrict__ Hprev, __bf16* __restrict__ hs) {
    const int d = blockIdx.x * 256 + threadIdx.x;
    const int c = blockIdx.y;
    const int b = blockIdx.z;
    const float a = A[d];
    float h = Hprev[((size_t)b * CC + c) * DD + d];
    const size_t base = ((size_t)b * SS + (size_t)c * LL) * DD + d;
    const float* xp = x + base;
    __bf16* hp = hs + base;
#pragma unroll 8
    for (int t = 0; t < LL; ++t) {
        h = fmaf(h, a, xp[(size_t)t * DD]);
        hp[(size_t)t * DD] = (__bf16)h;
    }
}

// ---------------- BC transpose + cast: BCt[o][d] = bf16(BC[d][o]) ----------------
// grid (OO/32, DD/32), block 256 (32x8 logical).
__global__ void transpose_cast(const float* __restrict__ BC, __bf16* __restrict__ BCt) {
    __shared__ float tile[32][33];
    const int tx = threadIdx.x & 31;
    const int ty = threadIdx.x >> 5;   // 0..7
    const int o0 = blockIdx.x * 32;
    const int d0 = blockIdx.y * 32;
#pragma unroll
    for (int i = 0; i < 4; ++i) {
        const int dd = ty + i * 8;
        tile[dd][tx] = BC[(size_t)(d0 + dd) * OO + o0 + tx];
    }
    __syncthreads();
#pragma unroll
    for (int i = 0; i < 4; ++i) {
        const int oo = ty + i * 8;
        BCt[(size_t)(o0 + oo) * DD + d0 + tx] = (__bf16)tile[tx][oo];
    }
}

// ---------------- GEMM: C[m,n] = sum_k A[m,k] * Bt[n,k]  (m97 structure) ----------------
#define TM 128
#define TN 128
#define TK 32

__device__ __forceinline__ void async16(void* lds, const void* g) {
    __builtin_amdgcn_global_load_lds(
        (__attribute__((address_space(1))) void*)(void*)g,
        (__attribute__((address_space(3))) void*)lds, 16, 0, 0);
}

__global__ __launch_bounds__(256) void gemm_bt(const __bf16* __restrict__ Am,
                                               const __bf16* __restrict__ Bt,
                                               float* __restrict__ C) {
    __shared__ __align__(16) __bf16 As[TM * TK];
    __shared__ __align__(16) __bf16 Bs[TN * TK];

    const int tid = threadIdx.x;
    const int wave = tid >> 6;
    const int lane = tid & 63;
    const int wm = (wave >> 1) * 64;
    const int wn = (wave & 1) * 64;
    const int lanelo = lane & 15;
    const int quad = lane >> 4;
    const int tile_m = blockIdx.y * TM;
    const int tile_n = blockIdx.x * TN;

    const int cid0 = tid;         // 16B chunk ids
    const int cid1 = tid + 256;
    const int r0 = cid0 >> 2, q0 = (cid0 & 3) * 8;
    const int r1 = cid1 >> 2, q1 = (cid1 & 3) * 8;

    floatx4 acc[4][4];
#pragma unroll
    for (int i = 0; i < 4; ++i)
#pragma unroll
        for (int j = 0; j < 4; ++j) acc[i][j] = (floatx4){0.f, 0.f, 0.f, 0.f};

    for (int k0 = 0; k0 < KK; k0 += TK) {
        __syncthreads();
        // stage A tile [TM][TK] and B tile [TN][TK], contiguous chunk order
        async16(&As[cid0 * 8], Am + (size_t)(tile_m + r0) * KK + k0 + q0);
        async16(&As[cid1 * 8], Am + (size_t)(tile_m + r1) * KK + k0 + q1);
        async16(&Bs[cid0 * 8], Bt + (size_t)(tile_n + r0) * KK + k0 + q0);
        async16(&Bs[cid1 * 8], Bt + (size_t)(tile_n + r1) * KK + k0 + q1);
        __syncthreads();

        bf16x8 af[4], bf[4];
#pragma unroll
        for (int i = 0; i < 4; ++i)
            af[i] = *(const bf16x8*)(&As[(wm + i * 16 + lanelo) * TK + quad * 8]);
#pragma unroll
        for (int j = 0; j < 4; ++j)
            bf[j] = *(const bf16x8*)(&Bs[(wn + j * 16 + lanelo) * TK + quad * 8]);

#pragma unroll
        for (int i = 0; i < 4; ++i)
#pragma unroll
            for (int j = 0; j < 4; ++j)
                acc[i][j] = __builtin_amdgcn_mfma_f32_16x16x32_bf16(af[i], bf[j], acc[i][j], 0, 0, 0);
    }

    // epilogue: row = quad*4 + reg, col = lanelo
#pragma unroll
    for (int i = 0; i < 4; ++i) {
        const int row = tile_m + wm + i * 16 + quad * 4;
#pragma unroll
        for (int r = 0; r < 4; ++r) {
            float* crow = C + (size_t)(row + r) * NN + tile_n + wn + lanelo;
#pragma unroll
            for (int j = 0; j < 4; ++j) crow[j * 16] = acc[i][j][r];
        }
    }
}

extern "C" void kernel_launch(void* const* d_in, const int* in_sizes, int n_in,
                              void* d_out, int out_size, void* d_ws, size_t ws_size,
                              hipStream_t stream) {
    const float* x  = (const float*)d_in[0];   // [B,S,D]
    const float* A  = (const float*)d_in[1];   // [D]
    const float* BC = (const float*)d_in[2];   // [D,O]
    float* out = (float*)d_out;                // [B,S,O]

    char* ws = (char*)d_ws;
    __bf16* hs   = (__bf16*)ws;                                  // 33,554,432 B
    float* carry = (float*)(ws + 33554432);                      // 1 MB
    float* Hprev = (float*)(ws + 33554432 + 1048576);            // 1 MB
    __bf16* BCt  = (__bf16*)(ws + 33554432 + 2097152);           // 2 MB

    scan_carry<<<dim3(DD / 256, CC, BB), 256, 0, stream>>>(x, A, carry);
    transpose_cast<<<dim3(OO / 32, DD / 32), 256, 0, stream>>>(BC, BCt);
    chunk_scan<<<dim3(BB * DD / 256), 256, 0, stream>>>(carry, A, Hprev);
    scan_emit<<<dim3(DD / 256, CC, BB), 256, 0, stream>>>(x, A, Hprev, hs);
    gemm_bt<<<dim3(NN / TN, MM / TM), 256, 0, stream>>>(hs, BCt, out);
}

// Round 2
// 180.430 us; speedup vs baseline: 1.0314x; 1.0314x over previous
//
#include <hip/hip_runtime.h>
#include <hip/hip_bf16.h>

// Problem constants
#define BB 8
#define SS 2048
#define DD 1024
#define OO 1024
#define MM (BB * SS)   // 16384
#define KK DD          // 1024
#define NN OO          // 1024
#define CC 32          // chunks
#define LL 64          // chunk length (CC*LL == SS)

typedef __bf16 bf16x8 __attribute__((ext_vector_type(8)));
typedef __bf16 bf16x4 __attribute__((ext_vector_type(4)));
typedef float floatx4 __attribute__((ext_vector_type(4)));

// ---------------- Pass A: per-chunk carries ----------------
// grid (CC, BB), block 256. Block streams its chunk's 256 KB contiguously,
// 4 KB row per step via float4 (16 B/lane).
__global__ __launch_bounds__(256) void scan_carry(const float* __restrict__ x,
                                                  const float* __restrict__ A,
                                                  float* __restrict__ carry) {
    const int i4 = threadIdx.x;            // float4 index over D (0..255)
    const int c = blockIdx.x;
    const int b = blockIdx.y;
    const float4 a = ((const float4*)A)[i4];
    const float4* xp = (const float4*)(x + ((size_t)b * SS + (size_t)c * LL) * DD) + i4;
    float4 h = make_float4(0.f, 0.f, 0.f, 0.f);
#pragma unroll 8
    for (int t = 0; t < LL; ++t) {
        const float4 v = xp[(size_t)t * (DD / 4)];
        h.x = fmaf(h.x, a.x, v.x);
        h.y = fmaf(h.y, a.y, v.y);
        h.z = fmaf(h.z, a.z, v.z);
        h.w = fmaf(h.w, a.w, v.w);
    }
    ((float4*)carry)[((size_t)b * CC + c) * (DD / 4) + i4] = h;
}

// ---------------- Pass B: chunk-level scan ----------------
// grid (BB*DD/256), block 256. Hprev[(b*CC+c)*DD+d] = true state entering chunk c.
__global__ void chunk_scan(const float* __restrict__ carry, const float* __restrict__ A,
                           float* __restrict__ Hprev) {
    const int idx = blockIdx.x * 256 + threadIdx.x;   // b*DD + d
    const int d = idx & (DD - 1);
    const int b = idx >> 10;
    const float a = A[d];
    float aL = a;
#pragma unroll
    for (int i = 0; i < 6; ++i) aL *= aL;             // a^64
    float h = 0.f;
#pragma unroll
    for (int c = 0; c < CC; ++c) {
        const size_t o = ((size_t)b * CC + c) * DD + d;
        Hprev[o] = h;
        h = fmaf(aL, h, carry[o]);
    }
}

// ---------------- Pass C: emit hs (bf16) ----------------
// grid (CC, BB), block 256. Contiguous float4 reads, bf16x4 (8 B/lane) writes.
__global__ __launch_bounds__(256) void scan_emit(const float* __restrict__ x,
                                                 const float* __restrict__ A,
                                                 const float* __restrict__ Hprev,
                                                 __bf16* __restrict__ hs) {
    const int i4 = threadIdx.x;
    const int c = blockIdx.x;
    const int b = blockIdx.y;
    const float4 a = ((const float4*)A)[i4];
    float4 h = ((const float4*)Hprev)[((size_t)b * CC + c) * (DD / 4) + i4];
    const size_t base = ((size_t)b * SS + (size_t)c * LL) * DD;
    const float4* xp = (const float4*)(x + base) + i4;
    bf16x4* hp = (bf16x4*)(hs + base) + i4;
#pragma unroll 4
    for (int t = 0; t < LL; ++t) {
        const float4 v = xp[(size_t)t * (DD / 4)];
        h.x = fmaf(h.x, a.x, v.x);
        h.y = fmaf(h.y, a.y, v.y);
        h.z = fmaf(h.z, a.z, v.z);
        h.w = fmaf(h.w, a.w, v.w);
        bf16x4 o;
        o[0] = (__bf16)h.x; o[1] = (__bf16)h.y; o[2] = (__bf16)h.z; o[3] = (__bf16)h.w;
        hp[(size_t)t * (DD / 4)] = o;
    }
}

// ---------------- BC transpose + cast: BCt[o][d] = bf16(BC[d][o]) ----------------
// grid (OO/32, DD/32), block 256 (32x8 logical).
__global__ void transpose_cast(const float* __restrict__ BC, __bf16* __restrict__ BCt) {
    __shared__ float tile[32][33];
    const int tx = threadIdx.x & 31;
    const int ty = threadIdx.x >> 5;   // 0..7
    const int o0 = blockIdx.x * 32;
    const int d0 = blockIdx.y * 32;
#pragma unroll
    for (int i = 0; i < 4; ++i) {
        const int dd = ty + i * 8;
        tile[dd][tx] = BC[(size_t)(d0 + dd) * OO + o0 + tx];
    }
    __syncthreads();
#pragma unroll
    for (int i = 0; i < 4; ++i) {
        const int oo = ty + i * 8;
        BCt[(size_t)(o0 + oo) * DD + d0 + tx] = (__bf16)tile[tx][oo];
    }
}

// ---------------- GEMM: C[m,n] = sum_k A[m,k] * Bt[n,k]  (m97 structure) ----------------
// grid (MM/TM, NN/TN): consecutive block ids share tile_n -> per-XCD L2 keeps
// the B column tile hot while streaming A m-tiles.
#define TM 128
#define TN 128
#define TK 32

__device__ __forceinline__ void async16(void* lds, const void* g) {
    __builtin_amdgcn_global_load_lds(
        (__attribute__((address_space(1))) void*)(void*)g,
        (__attribute__((address_space(3))) void*)lds, 16, 0, 0);
}

__global__ __launch_bounds__(256) void gemm_bt(const __bf16* __restrict__ Am,
                                               const __bf16* __restrict__ Bt,
                                               float* __restrict__ C) {
    __shared__ __align__(16) __bf16 As[TM * TK];
    __shared__ __align__(16) __bf16 Bs[TN * TK];

    const int tid = threadIdx.x;
    const int wave = tid >> 6;
    const int lane = tid & 63;
    const int wm = (wave >> 1) * 64;
    const int wn = (wave & 1) * 64;
    const int lanelo = lane & 15;
    const int quad = lane >> 4;
    const int tile_m = blockIdx.x * TM;   // m varies fastest across block ids
    const int tile_n = blockIdx.y * TN;

    const int cid0 = tid;         // 16B chunk ids
    const int cid1 = tid + 256;
    const int r0 = cid0 >> 2, q0 = (cid0 & 3) * 8;
    const int r1 = cid1 >> 2, q1 = (cid1 & 3) * 8;

    floatx4 acc[4][4];
#pragma unroll
    for (int i = 0; i < 4; ++i)
#pragma unroll
        for (int j = 0; j < 4; ++j) acc[i][j] = (floatx4){0.f, 0.f, 0.f, 0.f};

    for (int k0 = 0; k0 < KK; k0 += TK) {
        __syncthreads();
        // stage A tile [TM][TK] and B tile [TN][TK], contiguous chunk order
        async16(&As[cid0 * 8], Am + (size_t)(tile_m + r0) * KK + k0 + q0);
        async16(&As[cid1 * 8], Am + (size_t)(tile_m + r1) * KK + k0 + q1);
        async16(&Bs[cid0 * 8], Bt + (size_t)(tile_n + r0) * KK + k0 + q0);
        async16(&Bs[cid1 * 8], Bt + (size_t)(tile_n + r1) * KK + k0 + q1);
        __syncthreads();

        bf16x8 af[4], bf[4];
#pragma unroll
        for (int i = 0; i < 4; ++i)
            af[i] = *(const bf16x8*)(&As[(wm + i * 16 + lanelo) * TK + quad * 8]);
#pragma unroll
        for (int j = 0; j < 4; ++j)
            bf[j] = *(const bf16x8*)(&Bs[(wn + j * 16 + lanelo) * TK + quad * 8]);

#pragma unroll
        for (int i = 0; i < 4; ++i)
#pragma unroll
            for (int j = 0; j < 4; ++j)
                acc[i][j] = __builtin_amdgcn_mfma_f32_16x16x32_bf16(af[i], bf[j], acc[i][j], 0, 0, 0);
    }

    // epilogue: row = quad*4 + reg, col = lanelo
#pragma unroll
    for (int i = 0; i < 4; ++i) {
        const int row = tile_m + wm + i * 16 + quad * 4;
#pragma unroll
        for (int r = 0; r < 4; ++r) {
            float* crow = C + (size_t)(row + r) * NN + tile_n + wn + lanelo;
#pragma unroll
            for (int j = 0; j < 4; ++j) crow[j * 16] = acc[i][j][r];
        }
    }
}

extern "C" void kernel_launch(void* const* d_in, const int* in_sizes, int n_in,
                              void* d_out, int out_size, void* d_ws, size_t ws_size,
                              hipStream_t stream) {
    const float* x  = (const float*)d_in[0];   // [B,S,D]
    const float* A  = (const float*)d_in[1];   // [D]
    const float* BC = (const float*)d_in[2];   // [D,O]
    float* out = (float*)d_out;                // [B,S,O]

    char* ws = (char*)d_ws;
    __bf16* hs   = (__bf16*)ws;                                  // 33,554,432 B
    float* carry = (float*)(ws + 33554432);                      // 1 MB
    float* Hprev = (float*)(ws + 33554432 + 1048576);            // 1 MB
    __bf16* BCt  = (__bf16*)(ws + 33554432 + 2097152);           // 2 MB

    scan_carry<<<dim3(CC, BB), 256, 0, stream>>>(x, A, carry);
    transpose_cast<<<dim3(OO / 32, DD / 32), 256, 0, stream>>>(BC, BCt);
    chunk_scan<<<dim3(BB * DD / 256), 256, 0, stream>>>(carry, A, Hprev);
    scan_emit<<<dim3(CC, BB), 256, 0, stream>>>(x, A, Hprev, hs);
    gemm_bt<<<dim3(MM / TM, NN / TN), 256, 0, stream>>>(hs, BCt, out);
}

// Round 3
// 179.028 us; speedup vs baseline: 1.0395x; 1.0078x over previous
//
#include <hip/hip_runtime.h>
#include <hip/hip_bf16.h>

// Problem constants
#define BB 8
#define SS 2048
#define DD 1024
#define OO 1024
#define MM (BB * SS)   // 16384
#define KK DD          // 1024
#define NN OO          // 1024
#define CC 64          // chunks
#define LL 32          // chunk length (CC*LL == SS)

typedef __bf16 bf16x8 __attribute__((ext_vector_type(8)));
typedef __bf16 bf16x4 __attribute__((ext_vector_type(4)));
typedef float floatx4 __attribute__((ext_vector_type(4)));

__device__ __forceinline__ float4 fma4(float4 h, float4 a, float4 v) {
    h.x = fmaf(h.x, a.x, v.x);
    h.y = fmaf(h.y, a.y, v.y);
    h.z = fmaf(h.z, a.z, v.z);
    h.w = fmaf(h.w, a.w, v.w);
    return h;
}

// ---------------- Kernel 1: fused per-chunk carries + BC transpose/cast ----------------
// Blocks [0, BB*CC): scan_carry for (b = id/CC, c = id%CC). Each block streams a
// contiguous 128 KB chunk, 8 float4 loads batched in-flight per thread.
// Blocks [BB*CC, BB*CC + 1024): transpose BCt[o][d] = bf16(BC[d][o]), 32x32 tiles.
__global__ __launch_bounds__(256) void prep(const float* __restrict__ x,
                                            const float* __restrict__ A,
                                            float* __restrict__ carry,
                                            const float* __restrict__ BC,
                                            __bf16* __restrict__ BCt) {
    __shared__ float tile[32][33];
    const int id = blockIdx.x;
    if (id < BB * CC) {
        const int c = id & (CC - 1);
        const int b = id >> 6;          // id / CC
        const int i4 = threadIdx.x;     // float4 index over D (0..255)
        const float4 a = ((const float4*)A)[i4];
        const float4* xp = (const float4*)(x + ((size_t)b * SS + (size_t)c * LL) * DD) + i4;
        float4 h = make_float4(0.f, 0.f, 0.f, 0.f);
#pragma unroll
        for (int t0 = 0; t0 < LL; t0 += 8) {
            float4 v[8];
#pragma unroll
            for (int u = 0; u < 8; ++u) v[u] = xp[(size_t)(t0 + u) * (DD / 4)];
#pragma unroll
            for (int u = 0; u < 8; ++u) h = fma4(h, a, v[u]);
        }
        ((float4*)carry)[((size_t)b * CC + c) * (DD / 4) + i4] = h;
    } else {
        const int t = id - BB * CC;
        const int o0 = (t & 31) * 32;
        const int d0 = (t >> 5) * 32;
        const int tx = threadIdx.x & 31;
        const int ty = threadIdx.x >> 5;   // 0..7
#pragma unroll
        for (int i = 0; i < 4; ++i) {
            const int dd = ty + i * 8;
            tile[dd][tx] = BC[(size_t)(d0 + dd) * OO + o0 + tx];
        }
        __syncthreads();
#pragma unroll
        for (int i = 0; i < 4; ++i) {
            const int oo = ty + i * 8;
            BCt[(size_t)(o0 + oo) * DD + d0 + tx] = (__bf16)tile[tx][oo];
        }
    }
}

// ---------------- Kernel 2: chunk-level scan ----------------
// grid (BB*DD/256), block 256. All CC carries prefetched into registers (64
// independent loads in flight), then in-register sequential scan.
__global__ __launch_bounds__(256) void chunk_scan(const float* __restrict__ carry,
                                                  const float* __restrict__ A,
                                                  float* __restrict__ Hprev) {
    const int idx = blockIdx.x * 256 + threadIdx.x;   // b*DD + d
    const int d = idx & (DD - 1);
    const int b = idx >> 10;
    const float a = A[d];
    float aL = a;
#pragma unroll
    for (int i = 0; i < 5; ++i) aL *= aL;             // a^32 (LL=32)
    float ca[CC];
#pragma unroll
    for (int c = 0; c < CC; ++c)
        ca[c] = carry[((size_t)b * CC + c) * DD + d];
    float h = 0.f;
#pragma unroll
    for (int c = 0; c < CC; ++c) {
        Hprev[((size_t)b * CC + c) * DD + d] = h;
        h = fmaf(aL, h, ca[c]);
    }
}

// ---------------- Kernel 3: emit hs (bf16) ----------------
// grid (BB*CC), block 256. Batched float4 loads, bf16x4 stores.
__global__ __launch_bounds__(256) void scan_emit(const float* __restrict__ x,
                                                 const float* __restrict__ A,
                                                 const float* __restrict__ Hprev,
                                                 __bf16* __restrict__ hs) {
    const int id = blockIdx.x;
    const int c = id & (CC - 1);
    const int b = id >> 6;
    const int i4 = threadIdx.x;
    const float4 a = ((const float4*)A)[i4];
    float4 h = ((const float4*)Hprev)[((size_t)b * CC + c) * (DD / 4) + i4];
    const size_t base = ((size_t)b * SS + (size_t)c * LL) * DD;
    const float4* xp = (const float4*)(x + base) + i4;
    bf16x4* hp = (bf16x4*)(hs + base) + i4;
#pragma unroll
    for (int t0 = 0; t0 < LL; t0 += 8) {
        float4 v[8];
#pragma unroll
        for (int u = 0; u < 8; ++u) v[u] = xp[(size_t)(t0 + u) * (DD / 4)];
#pragma unroll
        for (int u = 0; u < 8; ++u) {
            h = fma4(h, a, v[u]);
            bf16x4 o;
            o[0] = (__bf16)h.x; o[1] = (__bf16)h.y; o[2] = (__bf16)h.z; o[3] = (__bf16)h.w;
            hp[(size_t)(t0 + u) * (DD / 4)] = o;
        }
    }
}

// ---------------- GEMM: C[m,n] = sum_k A[m,k] * Bt[n,k]  (m97 structure) ----------------
// grid (MM/TM, NN/TN): consecutive block ids share tile_n -> per-XCD L2 keeps
// the B column tile hot while streaming A m-tiles.
#define TM 128
#define TN 128
#define TK 32

__device__ __forceinline__ void async16(void* lds, const void* g) {
    __builtin_amdgcn_global_load_lds(
        (__attribute__((address_space(1))) void*)(void*)g,
        (__attribute__((address_space(3))) void*)lds, 16, 0, 0);
}

__global__ __launch_bounds__(256) void gemm_bt(const __bf16* __restrict__ Am,
                                               const __bf16* __restrict__ Bt,
                                               float* __restrict__ C) {
    __shared__ __align__(16) __bf16 As[TM * TK];
    __shared__ __align__(16) __bf16 Bs[TN * TK];

    const int tid = threadIdx.x;
    const int wave = tid >> 6;
    const int lane = tid & 63;
    const int wm = (wave >> 1) * 64;
    const int wn = (wave & 1) * 64;
    const int lanelo = lane & 15;
    const int quad = lane >> 4;
    const int tile_m = blockIdx.x * TM;   // m varies fastest across block ids
    const int tile_n = blockIdx.y * TN;

    const int cid0 = tid;         // 16B chunk ids
    const int cid1 = tid + 256;
    const int r0 = cid0 >> 2, q0 = (cid0 & 3) * 8;
    const int r1 = cid1 >> 2, q1 = (cid1 & 3) * 8;

    floatx4 acc[4][4];
#pragma unroll
    for (int i = 0; i < 4; ++i)
#pragma unroll
        for (int j = 0; j < 4; ++j) acc[i][j] = (floatx4){0.f, 0.f, 0.f, 0.f};

    for (int k0 = 0; k0 < KK; k0 += TK) {
        __syncthreads();
        // stage A tile [TM][TK] and B tile [TN][TK], contiguous chunk order
        async16(&As[cid0 * 8], Am + (size_t)(tile_m + r0) * KK + k0 + q0);
        async16(&As[cid1 * 8], Am + (size_t)(tile_m + r1) * KK + k0 + q1);
        async16(&Bs[cid0 * 8], Bt + (size_t)(tile_n + r0) * KK + k0 + q0);
        async16(&Bs[cid1 * 8], Bt + (size_t)(tile_n + r1) * KK + k0 + q1);
        __syncthreads();

        bf16x8 af[4], bf[4];
#pragma unroll
        for (int i = 0; i < 4; ++i)
            af[i] = *(const bf16x8*)(&As[(wm + i * 16 + lanelo) * TK + quad * 8]);
#pragma unroll
        for (int j = 0; j < 4; ++j)
            bf[j] = *(const bf16x8*)(&Bs[(wn + j * 16 + lanelo) * TK + quad * 8]);

#pragma unroll
        for (int i = 0; i < 4; ++i)
#pragma unroll
            for (int j = 0; j < 4; ++j)
                acc[i][j] = __builtin_amdgcn_mfma_f32_16x16x32_bf16(af[i], bf[j], acc[i][j], 0, 0, 0);
    }

    // epilogue: row = quad*4 + reg, col = lanelo
#pragma unroll
    for (int i = 0; i < 4; ++i) {
        const int row = tile_m + wm + i * 16 + quad * 4;
#pragma unroll
        for (int r = 0; r < 4; ++r) {
            float* crow = C + (size_t)(row + r) * NN + tile_n + wn + lanelo;
#pragma unroll
            for (int j = 0; j < 4; ++j) crow[j * 16] = acc[i][j][r];
        }
    }
}

extern "C" void kernel_launch(void* const* d_in, const int* in_sizes, int n_in,
                              void* d_out, int out_size, void* d_ws, size_t ws_size,
                              hipStream_t stream) {
    const float* x  = (const float*)d_in[0];   // [B,S,D]
    const float* A  = (const float*)d_in[1];   // [D]
    const float* BC = (const float*)d_in[2];   // [D,O]
    float* out = (float*)d_out;                // [B,S,O]

    char* ws = (char*)d_ws;
    __bf16* hs   = (__bf16*)ws;                                  // 33,554,432 B
    float* carry = (float*)(ws + 33554432);                      // 2 MB (BB*CC*DD*4)
    float* Hprev = (float*)(ws + 33554432 + 2097152);            // 2 MB
    __bf16* BCt  = (__bf16*)(ws + 33554432 + 4194304);           // 2 MB

    prep<<<dim3(BB * CC + 1024), 256, 0, stream>>>(x, A, carry, BC, BCt);
    chunk_scan<<<dim3(BB * DD / 256), 256, 0, stream>>>(carry, A, Hprev);
    scan_emit<<<dim3(BB * CC), 256, 0, stream>>>(x, A, Hprev, hs);
    gemm_bt<<<dim3(MM / TM, NN / TN), 256, 0, stream>>>(hs, BCt, out);
}

// Round 4
// 179.000 us; speedup vs baseline: 1.0396x; 1.0002x over previous
//
#include <hip/hip_runtime.h>
#include <hip/hip_bf16.h>

// Problem constants
#define BB 8
#define SS 2048
#define DD 1024
#define OO 1024
#define MM (BB * SS)   // 16384
#define KK DD          // 1024
#define NN OO          // 1024
#define CC 64          // chunks
#define LL 32          // chunk length (CC*LL == SS)

typedef __bf16 bf16x8 __attribute__((ext_vector_type(8)));
typedef __bf16 bf16x4 __attribute__((ext_vector_type(4)));
typedef float floatx4 __attribute__((ext_vector_type(4)));

__device__ __forceinline__ float4 fma4(float4 h, float4 a, float4 v) {
    h.x = fmaf(h.x, a.x, v.x);
    h.y = fmaf(h.y, a.y, v.y);
    h.z = fmaf(h.z, a.z, v.z);
    h.w = fmaf(h.w, a.w, v.w);
    return h;
}

// ---------------- Kernel 1: fused per-chunk carries + BC transpose/cast ----------------
// Blocks [0, BB*CC): carry for (b = id/CC, c = id%CC): contiguous 128 KB stream.
// Blocks [BB*CC, BB*CC + 1024): BCt[o][d] = bf16(BC[d][o]), 32x32 tiles.
__global__ __launch_bounds__(256) void prep(const float* __restrict__ x,
                                            const float* __restrict__ A,
                                            float* __restrict__ carry,
                                            const float* __restrict__ BC,
                                            __bf16* __restrict__ BCt) {
    __shared__ float tile[32][33];
    const int id = blockIdx.x;
    if (id < BB * CC) {
        const int c = id & (CC - 1);
        const int b = id >> 6;          // id / CC
        const int i4 = threadIdx.x;     // float4 index over D (0..255)
        const float4 a = ((const float4*)A)[i4];
        const float4* xp = (const float4*)(x + ((size_t)b * SS + (size_t)c * LL) * DD) + i4;
        float4 h = make_float4(0.f, 0.f, 0.f, 0.f);
#pragma unroll
        for (int t0 = 0; t0 < LL; t0 += 8) {
            float4 v[8];
#pragma unroll
            for (int u = 0; u < 8; ++u) v[u] = xp[(size_t)(t0 + u) * (DD / 4)];
#pragma unroll
            for (int u = 0; u < 8; ++u) h = fma4(h, a, v[u]);
        }
        ((float4*)carry)[((size_t)b * CC + c) * (DD / 4) + i4] = h;
    } else {
        const int t = id - BB * CC;
        const int o0 = (t & 31) * 32;
        const int d0 = (t >> 5) * 32;
        const int tx = threadIdx.x & 31;
        const int ty = threadIdx.x >> 5;   // 0..7
#pragma unroll
        for (int i = 0; i < 4; ++i) {
            const int dd = ty + i * 8;
            tile[dd][tx] = BC[(size_t)(d0 + dd) * OO + o0 + tx];
        }
        __syncthreads();
#pragma unroll
        for (int i = 0; i < 4; ++i) {
            const int oo = ty + i * 8;
            BCt[(size_t)(o0 + oo) * DD + d0 + tx] = (__bf16)tile[tx][oo];
        }
    }
}

// ---------------- Kernel 2: emit hs (bf16), chunk prefix computed in-kernel ----------------
// grid (BB*CC), block 256. Prefix over the 2 MB L2-resident carry array, then
// contiguous float4 reads of x, bf16x4 stores of hs.
__global__ __launch_bounds__(256) void scan_emit(const float* __restrict__ x,
                                                 const float* __restrict__ A,
                                                 const float* __restrict__ carry,
                                                 __bf16* __restrict__ hs) {
    const int id = blockIdx.x;
    const int c = id & (CC - 1);
    const int b = id >> 6;
    const int i4 = threadIdx.x;
    const float4 a = ((const float4*)A)[i4];
    // aL = a^LL componentwise (LL = 32 -> 5 squarings)
    float4 aL = a;
#pragma unroll
    for (int i = 0; i < 5; ++i) { aL.x *= aL.x; aL.y *= aL.y; aL.z *= aL.z; aL.w *= aL.w; }
    // Prefix: h entering chunk c = sum_{j<c} aL^(c-1-j) * carry[b,j]
    float4 h = make_float4(0.f, 0.f, 0.f, 0.f);
    const float4* cp = (const float4*)carry + (size_t)b * CC * (DD / 4) + i4;
    for (int j = 0; j < c; ++j) {
        const float4 cv = cp[(size_t)j * (DD / 4)];
        h.x = fmaf(h.x, aL.x, cv.x);
        h.y = fmaf(h.y, aL.y, cv.y);
        h.z = fmaf(h.z, aL.z, cv.z);
        h.w = fmaf(h.w, aL.w, cv.w);
    }
    const size_t base = ((size_t)b * SS + (size_t)c * LL) * DD;
    const float4* xp = (const float4*)(x + base) + i4;
    bf16x4* hp = (bf16x4*)(hs + base) + i4;
#pragma unroll
    for (int t0 = 0; t0 < LL; t0 += 8) {
        float4 v[8];
#pragma unroll
        for (int u = 0; u < 8; ++u) v[u] = xp[(size_t)(t0 + u) * (DD / 4)];
#pragma unroll
        for (int u = 0; u < 8; ++u) {
            h = fma4(h, a, v[u]);
            bf16x4 o;
            o[0] = (__bf16)h.x; o[1] = (__bf16)h.y; o[2] = (__bf16)h.z; o[3] = (__bf16)h.w;
            hp[(size_t)(t0 + u) * (DD / 4)] = o;
        }
    }
}

// ---------------- GEMM: C[m,n] = sum_k A[m,k] * Bt[n,k] ----------------
// Double-buffered LDS, ONE barrier per k-iter: stage tile k+1 into buf^1
// immediately after the barrier that publishes buf, so the global_load_lds
// for k+1 has a full iteration of ds_read+MFMA to cover its latency before
// the next barrier's vmcnt(0) drain.
#define TM 128
#define TN 128
#define TK 32
#define NITER (KK / TK)

__device__ __forceinline__ void async16(void* lds, const void* g) {
    __builtin_amdgcn_global_load_lds(
        (__attribute__((address_space(1))) void*)(void*)g,
        (__attribute__((address_space(3))) void*)lds, 16, 0, 0);
}

__global__ __launch_bounds__(256) void gemm_bt(const __bf16* __restrict__ Am,
                                               const __bf16* __restrict__ Bt,
                                               float* __restrict__ C) {
    __shared__ __align__(16) __bf16 As[2][TM * TK];
    __shared__ __align__(16) __bf16 Bs[2][TN * TK];

    const int tid = threadIdx.x;
    const int wave = tid >> 6;
    const int lane = tid & 63;
    const int wm = (wave >> 1) * 64;
    const int wn = (wave & 1) * 64;
    const int lanelo = lane & 15;
    const int quad = lane >> 4;
    const int tile_m = blockIdx.x * TM;   // m varies fastest across block ids
    const int tile_n = blockIdx.y * TN;

    const int cid0 = tid;         // 16B chunk ids
    const int cid1 = tid + 256;
    const int r0 = cid0 >> 2, q0 = (cid0 & 3) * 8;
    const int r1 = cid1 >> 2, q1 = (cid1 & 3) * 8;

    const __bf16* Ab = Am + (size_t)(tile_m + r0) * KK + q0;
    const __bf16* Ab1 = Am + (size_t)(tile_m + r1) * KK + q1;
    const __bf16* Bb = Bt + (size_t)(tile_n + r0) * KK + q0;
    const __bf16* Bb1 = Bt + (size_t)(tile_n + r1) * KK + q1;

    floatx4 acc[4][4];
#pragma unroll
    for (int i = 0; i < 4; ++i)
#pragma unroll
        for (int j = 0; j < 4; ++j) acc[i][j] = (floatx4){0.f, 0.f, 0.f, 0.f};

    // prologue: stage tile 0 into buffer 0
    async16(&As[0][cid0 * 8], Ab);
    async16(&As[0][cid1 * 8], Ab1);
    async16(&Bs[0][cid0 * 8], Bb);
    async16(&Bs[0][cid1 * 8], Bb1);

    int cur = 0;
    for (int i = 0; i < NITER; ++i) {
        __syncthreads();   // buf[cur] staging complete; buf[cur^1] readers of iter i-1 done
        if (i + 1 < NITER) {
            const int k = (i + 1) * TK;
            async16(&As[cur ^ 1][cid0 * 8], Ab + k);
            async16(&As[cur ^ 1][cid1 * 8], Ab1 + k);
            async16(&Bs[cur ^ 1][cid0 * 8], Bb + k);
            async16(&Bs[cur ^ 1][cid1 * 8], Bb1 + k);
        }

        bf16x8 af[4], bf[4];
#pragma unroll
        for (int ii = 0; ii < 4; ++ii)
            af[ii] = *(const bf16x8*)(&As[cur][(wm + ii * 16 + lanelo) * TK + quad * 8]);
#pragma unroll
        for (int j = 0; j < 4; ++j)
            bf[j] = *(const bf16x8*)(&Bs[cur][(wn + j * 16 + lanelo) * TK + quad * 8]);

#pragma unroll
        for (int ii = 0; ii < 4; ++ii)
#pragma unroll
            for (int j = 0; j < 4; ++j)
                acc[ii][j] = __builtin_amdgcn_mfma_f32_16x16x32_bf16(af[ii], bf[j], acc[ii][j], 0, 0, 0);
        cur ^= 1;
    }

    // epilogue: row = quad*4 + reg, col = lanelo
#pragma unroll
    for (int i = 0; i < 4; ++i) {
        const int row = tile_m + wm + i * 16 + quad * 4;
#pragma unroll
        for (int r = 0; r < 4; ++r) {
            float* crow = C + (size_t)(row + r) * NN + tile_n + wn + lanelo;
#pragma unroll
            for (int j = 0; j < 4; ++j) crow[j * 16] = acc[i][j][r];
        }
    }
}

extern "C" void kernel_launch(void* const* d_in, const int* in_sizes, int n_in,
                              void* d_out, int out_size, void* d_ws, size_t ws_size,
                              hipStream_t stream) {
    const float* x  = (const float*)d_in[0];   // [B,S,D]
    const float* A  = (const float*)d_in[1];   // [D]
    const float* BC = (const float*)d_in[2];   // [D,O]
    float* out = (float*)d_out;                // [B,S,O]

    char* ws = (char*)d_ws;
    __bf16* hs   = (__bf16*)ws;                                  // 33,554,432 B
    float* carry = (float*)(ws + 33554432);                      // 2 MB (BB*CC*DD*4)
    __bf16* BCt  = (__bf16*)(ws + 33554432 + 2097152);           // 2 MB

    prep<<<dim3(BB * CC + 1024), 256, 0, stream>>>(x, A, carry, BC, BCt);
    scan_emit<<<dim3(BB * CC), 256, 0, stream>>>(x, A, carry, hs);
    gemm_bt<<<dim3(MM / TM, NN / TN), 256, 0, stream>>>(hs, BCt, out);
}

// Round 5
// 176.685 us; speedup vs baseline: 1.0532x; 1.0131x over previous
//
#include <hip/hip_runtime.h>
#include <hip/hip_bf16.h>

// Problem constants
#define BB 8
#define SS 2048
#define DD 1024
#define OO 1024
#define MM (BB * SS)   // 16384
#define KK DD          // 1024
#define NN OO          // 1024
#define CC 64          // chunks
#define LL 32          // chunk length (CC*LL == SS)

typedef __bf16 bf16x8 __attribute__((ext_vector_type(8)));
typedef __bf16 bf16x4 __attribute__((ext_vector_type(4)));
typedef float floatx4 __attribute__((ext_vector_type(4)));

__device__ __forceinline__ float4 fma4(float4 h, float4 a, float4 v) {
    h.x = fmaf(h.x, a.x, v.x);
    h.y = fmaf(h.y, a.y, v.y);
    h.z = fmaf(h.z, a.z, v.z);
    h.w = fmaf(h.w, a.w, v.w);
    return h;
}

// ---------------- Kernel 1: fused per-chunk carries + BC transpose/cast ----------------
__global__ __launch_bounds__(256) void prep(const float* __restrict__ x,
                                            const float* __restrict__ A,
                                            float* __restrict__ carry,
                                            const float* __restrict__ BC,
                                            __bf16* __restrict__ BCt) {
    __shared__ float tile[32][33];
    const int id = blockIdx.x;
    if (id < BB * CC) {
        const int c = id & (CC - 1);
        const int b = id >> 6;          // id / CC
        const int i4 = threadIdx.x;     // float4 index over D (0..255)
        const float4 a = ((const float4*)A)[i4];
        const float4* xp = (const float4*)(x + ((size_t)b * SS + (size_t)c * LL) * DD) + i4;
        float4 h = make_float4(0.f, 0.f, 0.f, 0.f);
#pragma unroll
        for (int t0 = 0; t0 < LL; t0 += 8) {
            float4 v[8];
#pragma unroll
            for (int u = 0; u < 8; ++u) v[u] = xp[(size_t)(t0 + u) * (DD / 4)];
#pragma unroll
            for (int u = 0; u < 8; ++u) h = fma4(h, a, v[u]);
        }
        ((float4*)carry)[((size_t)b * CC + c) * (DD / 4) + i4] = h;
    } else {
        const int t = id - BB * CC;
        const int o0 = (t & 31) * 32;
        const int d0 = (t >> 5) * 32;
        const int tx = threadIdx.x & 31;
        const int ty = threadIdx.x >> 5;   // 0..7
#pragma unroll
        for (int i = 0; i < 4; ++i) {
            const int dd = ty + i * 8;
            tile[dd][tx] = BC[(size_t)(d0 + dd) * OO + o0 + tx];
        }
        __syncthreads();
#pragma unroll
        for (int i = 0; i < 4; ++i) {
            const int oo = ty + i * 8;
            BCt[(size_t)(o0 + oo) * DD + d0 + tx] = (__bf16)tile[tx][oo];
        }
    }
}

// ---------------- Kernel 2: emit hs (bf16), chunk prefix computed in-kernel ----------------
__global__ __launch_bounds__(256) void scan_emit(const float* __restrict__ x,
                                                 const float* __restrict__ A,
                                                 const float* __restrict__ carry,
                                                 __bf16* __restrict__ hs) {
    const int id = blockIdx.x;
    const int c = id & (CC - 1);
    const int b = id >> 6;
    const int i4 = threadIdx.x;
    const float4 a = ((const float4*)A)[i4];
    float4 aL = a;
#pragma unroll
    for (int i = 0; i < 5; ++i) { aL.x *= aL.x; aL.y *= aL.y; aL.z *= aL.z; aL.w *= aL.w; }
    float4 h = make_float4(0.f, 0.f, 0.f, 0.f);
    const float4* cp = (const float4*)carry + (size_t)b * CC * (DD / 4) + i4;
    for (int j = 0; j < c; ++j) {
        const float4 cv = cp[(size_t)j * (DD / 4)];
        h.x = fmaf(h.x, aL.x, cv.x);
        h.y = fmaf(h.y, aL.y, cv.y);
        h.z = fmaf(h.z, aL.z, cv.z);
        h.w = fmaf(h.w, aL.w, cv.w);
    }
    const size_t base = ((size_t)b * SS + (size_t)c * LL) * DD;
    const float4* xp = (const float4*)(x + base) + i4;
    bf16x4* hp = (bf16x4*)(hs + base) + i4;
#pragma unroll
    for (int t0 = 0; t0 < LL; t0 += 8) {
        float4 v[8];
#pragma unroll
        for (int u = 0; u < 8; ++u) v[u] = xp[(size_t)(t0 + u) * (DD / 4)];
#pragma unroll
        for (int u = 0; u < 8; ++u) {
            h = fma4(h, a, v[u]);
            bf16x4 o;
            o[0] = (__bf16)h.x; o[1] = (__bf16)h.y; o[2] = (__bf16)h.z; o[3] = (__bf16)h.w;
            hp[(size_t)(t0 + u) * (DD / 4)] = o;
        }
    }
}

// ---------------- GEMM: C[m,n] = sum_k A[m,k] * Bt[n,k] ----------------
// Double-buffered, one barrier/iter, + XOR bank swizzle:
// chunk (row r, kgroup q) lives at LDS slot r*4 + (q ^ ((r>>1)&3)).
// Staging keeps the contiguous lane->LDS mapping and permutes the GLOBAL
// source chunk instead (16B swaps within each row's 64B segment, coalescing
// unchanged). Reads use kgroup = quad ^ ((lanelo>>1)&3), giving bank0 =
// 16*(lanelo&1) + 4*(quad^fs): 8 distinct bank-quads x 2 lanes per 16-lane
// phase = 2-way = conflict-free (m136).
#define TM 128
#define TN 128
#define TK 32
#define NITER (KK / TK)

__device__ __forceinline__ void async16(void* lds, const void* g) {
    __builtin_amdgcn_global_load_lds(
        (__attribute__((address_space(1))) void*)(void*)g,
        (__attribute__((address_space(3))) void*)lds, 16, 0, 0);
}

__global__ __launch_bounds__(256) void gemm_bt(const __bf16* __restrict__ Am,
                                               const __bf16* __restrict__ Bt,
                                               float* __restrict__ C) {
    __shared__ __align__(16) __bf16 As[2][TM * TK];
    __shared__ __align__(16) __bf16 Bs[2][TN * TK];

    const int tid = threadIdx.x;
    const int wave = tid >> 6;
    const int lane = tid & 63;
    const int wm = (wave >> 1) * 64;
    const int wn = (wave & 1) * 64;
    const int lanelo = lane & 15;
    const int quad = lane >> 4;
    const int tile_m = blockIdx.x * TM;   // m varies fastest across block ids
    const int tile_n = blockIdx.y * TN;

    // staging: LDS slot cid holds global chunk (r, q) with q XOR-swizzled
    const int cid0 = tid;
    const int cid1 = tid + 256;
    const int r0 = cid0 >> 2, q0 = ((cid0 & 3) ^ ((r0 >> 1) & 3)) * 8;
    const int r1 = cid1 >> 2, q1 = ((cid1 & 3) ^ ((r1 >> 1) & 3)) * 8;

    const __bf16* Ab  = Am + (size_t)(tile_m + r0) * KK + q0;
    const __bf16* Ab1 = Am + (size_t)(tile_m + r1) * KK + q1;
    const __bf16* Bb  = Bt + (size_t)(tile_n + r0) * KK + q0;
    const __bf16* Bb1 = Bt + (size_t)(tile_n + r1) * KK + q1;

    // read-side swizzled k-group offset (elements)
    const int fs = (lanelo >> 1) & 3;
    const int kq = (quad ^ fs) * 8;

    floatx4 acc[4][4];
#pragma unroll
    for (int i = 0; i < 4; ++i)
#pragma unroll
        for (int j = 0; j < 4; ++j) acc[i][j] = (floatx4){0.f, 0.f, 0.f, 0.f};

    // prologue: stage tile 0 into buffer 0
    async16(&As[0][cid0 * 8], Ab);
    async16(&As[0][cid1 * 8], Ab1);
    async16(&Bs[0][cid0 * 8], Bb);
    async16(&Bs[0][cid1 * 8], Bb1);

    int cur = 0;
    for (int i = 0; i < NITER; ++i) {
        __syncthreads();   // buf[cur] staged; prior readers of buf[cur^1] done
        if (i + 1 < NITER) {
            const int k = (i + 1) * TK;
            async16(&As[cur ^ 1][cid0 * 8], Ab + k);
            async16(&As[cur ^ 1][cid1 * 8], Ab1 + k);
            async16(&Bs[cur ^ 1][cid0 * 8], Bb + k);
            async16(&Bs[cur ^ 1][cid1 * 8], Bb1 + k);
        }

        bf16x8 af[4], bf[4];
#pragma unroll
        for (int ii = 0; ii < 4; ++ii)
            af[ii] = *(const bf16x8*)(&As[cur][(wm + ii * 16 + lanelo) * TK + kq]);
#pragma unroll
        for (int j = 0; j < 4; ++j)
            bf[j] = *(const bf16x8*)(&Bs[cur][(wn + j * 16 + lanelo) * TK + kq]);

#pragma unroll
        for (int ii = 0; ii < 4; ++ii)
#pragma unroll
            for (int j = 0; j < 4; ++j)
                acc[ii][j] = __builtin_amdgcn_mfma_f32_16x16x32_bf16(af[ii], bf[j], acc[ii][j], 0, 0, 0);
        cur ^= 1;
    }

    // epilogue: row = quad*4 + reg, col = lanelo
#pragma unroll
    for (int i = 0; i < 4; ++i) {
        const int row = tile_m + wm + i * 16 + quad * 4;
#pragma unroll
        for (int r = 0; r < 4; ++r) {
            float* crow = C + (size_t)(row + r) * NN + tile_n + wn + lanelo;
#pragma unroll
            for (int j = 0; j < 4; ++j) crow[j * 16] = acc[i][j][r];
        }
    }
}

extern "C" void kernel_launch(void* const* d_in, const int* in_sizes, int n_in,
                              void* d_out, int out_size, void* d_ws, size_t ws_size,
                              hipStream_t stream) {
    const float* x  = (const float*)d_in[0];   // [B,S,D]
    const float* A  = (const float*)d_in[1];   // [D]
    const float* BC = (const float*)d_in[2];   // [D,O]
    float* out = (float*)d_out;                // [B,S,O]

    char* ws = (char*)d_ws;
    __bf16* hs   = (__bf16*)ws;                                  // 33,554,432 B
    float* carry = (float*)(ws + 33554432);                      // 2 MB (BB*CC*DD*4)
    __bf16* BCt  = (__bf16*)(ws + 33554432 + 2097152);           // 2 MB

    prep<<<dim3(BB * CC + 1024), 256, 0, stream>>>(x, A, carry, BC, BCt);
    scan_emit<<<dim3(BB * CC), 256, 0, stream>>>(x, A, carry, hs);
    gemm_bt<<<dim3(MM / TM, NN / TN), 256, 0, stream>>>(hs, BCt, out);
}